// Round 2
// baseline (918.027 us; speedup 1.0000x reference)
//
#include <hip/hip_runtime.h>

#define KREAL 19000
#define KP    19008      // K padded to multiple of 32
#define NSTEPS 594       // KP / 32
#define BM 128
#define BN 256
#define MBLK 64          // 8192 / BM
#define BATCH 8192
#define SDIM 256
#define PDIM 128
#define NPW  16
#define S2S  32          // samples per stage2 block
#define MAXBLK 272       // ceil bound: 8192/32 + 16 (pad per pathway)

typedef __attribute__((ext_vector_type(8))) short frag_ab;   // 8 bf16 = 4 VGPRs
typedef __attribute__((ext_vector_type(4))) float frag_cd;   // 4 fp32 acc

static __device__ __forceinline__ short f2bf(float f) {
    union { float f; unsigned u; } cv; cv.f = f;
    unsigned u = cv.u;
    u += 0x7fffu + ((u >> 16) & 1u);   // round-to-nearest-even
    return (short)(u >> 16);
}

static __device__ __forceinline__ short4 cvt4(float4 v) {
    short4 p;
    p.x = f2bf(v.x); p.y = f2bf(v.y); p.z = f2bf(v.z); p.w = f2bf(v.w);
    return p;
}

// ---------------------------------------------------------------------------
// Kernel 0: W1 [19000][256] fp32  ->  W1t [256][19008] bf16 (zero-padded K)
// ---------------------------------------------------------------------------
__global__ void transpose_w1(const float* __restrict__ W1, short* __restrict__ W1t) {
    __shared__ float tile[32][33];
    int k0 = blockIdx.x * 32;
    int n0 = blockIdx.y * 32;
    int tx = threadIdx.x & 31;
    int ty = threadIdx.x >> 5;           // 0..7
#pragma unroll
    for (int i = 0; i < 32; i += 8) {
        int k = k0 + ty + i;
        tile[ty + i][tx] = (k < KREAL) ? W1[(long)k * SDIM + n0 + tx] : 0.f;
    }
    __syncthreads();
#pragma unroll
    for (int i = 0; i < 32; i += 8) {
        int n = n0 + ty + i;
        W1t[(long)n * KP + k0 + tx] = f2bf(tile[tx][ty + i]);
    }
}

// ---------------------------------------------------------------------------
// Kernel 0b: bucket samples by pathway. 1 block x 1024 threads.
// Outputs: ord[MAXBLK*S2S] sample indices grouped by pathway (-1 pad),
//          blk_p[MAXBLK] pathway id per stage2 block (-1 = idle block).
// Each pathway's segment is padded to a multiple of S2S, so stage2 block g
// owns ord[g*S2S .. g*S2S+31], all of one pathway.
// ---------------------------------------------------------------------------
__global__ __launch_bounds__(1024)
void bucket(const int* __restrict__ drug_idx, const int* __restrict__ d2p,
            int* __restrict__ ord, int* __restrict__ blk_p) {
    __shared__ int cnt[NPW];
    __shared__ int pos[NPW];
    __shared__ int pstart[NPW];          // segment start, in blocks
    int t = threadIdx.x;
    if (t < NPW) { cnt[t] = 0; pos[t] = 0; }
    __syncthreads();

    int myp[8];
#pragma unroll
    for (int r = 0; r < 8; r++) {
        int i = t + r * 1024;
        myp[r] = d2p[drug_idx[i]];
        atomicAdd(&cnt[myp[r]], 1);
    }
    for (int i = t; i < MAXBLK * S2S; i += 1024) ord[i] = -1;
    if (t < MAXBLK) blk_p[t] = -1;
    __syncthreads();

    if (t == 0) {
        int bb = 0;
        for (int p = 0; p < NPW; p++) {
            pstart[p] = bb;
            bb += (cnt[p] + S2S - 1) / S2S;
        }
    }
    __syncthreads();

    if (t < NPW) {
        int p = t, nb = (cnt[p] + S2S - 1) / S2S, b0 = pstart[p];
        for (int j = 0; j < nb; j++) blk_p[b0 + j] = p;
    }
#pragma unroll
    for (int r = 0; r < 8; r++) {
        int i = t + r * 1024;
        int p = myp[r];
        int j = atomicAdd(&pos[p], 1);
        ord[pstart[p] * S2S + j] = i;
    }
}

// ---------------------------------------------------------------------------
// Kernel 1: split-K GEMM partials. pout[ch][8192][256] = x @ W1 (chunk ch)
// Pipelined: double-buffered LDS, ONE barrier per K-step, loads for step s+1
// issued before the barrier of step s (reg-staged, in flight across barrier).
// ---------------------------------------------------------------------------
__global__ __launch_bounds__(512, 2)
void gemm1(const float* __restrict__ x, const short* __restrict__ W1t,
           float* __restrict__ pout, int nch) {
    __shared__ short As[2][BM * 32];     // 2 x 8 KB   [m][k]
    __shared__ short Bs[2][BN * 32];     // 2 x 16 KB  [n][k] (B^T layout)

    int bid = blockIdx.x;
    int mb, ch;
    if (nch == 4) {
        // XCD-aware decode: chunk ch pinned to one XCD pair -> its 2.3 MB
        // W1t slice stays L2-resident. Bijective: bid = slot*8 + xcd.
        int xcd  = bid & 7;
        int slot = bid >> 3;             // 0..31
        ch = xcd >> 1;                   // 0..3
        mb = ((xcd & 1) << 5) | slot;    // 0..63
    } else {
        mb = bid % MBLK;
        ch = bid / MBLK;
    }
    int m0 = mb * BM;
    int s0 = (NSTEPS * ch) / nch;
    int s1 = (NSTEPS * (ch + 1)) / nch;

    int tid  = threadIdx.x;
    int wave = tid >> 6;
    int lane = tid & 63;
    int wr = wave >> 2, wc = wave & 3;
    int lrow = lane & 15;
    int lq   = lane >> 4;                // quad 0..3

    int k4 = (tid & 7) << 2;                                   // 0..28 floats
    const float* xp0 = x + (long)(m0 + (tid >> 3)) * KREAL + k4;
    const float* xp1 = xp0 + (long)64 * KREAL;
    const short* bp0 = W1t + (long)(tid >> 2) * KP + ((tid & 3) << 3);
    const short* bp1 = bp0 + (long)128 * KP;

    frag_cd acc[4][4];
#pragma unroll
    for (int i = 0; i < 4; i++)
#pragma unroll
        for (int j = 0; j < 4; j++) acc[i][j] = (frag_cd)(0.f);

    float4 ra0, ra1;
    int4   rb0, rb1;
    {   // prologue: load step s0 into regs
        int kb = s0 * 32;
        bool ok = (kb + k4 + 4 <= KREAL);
        ra0 = ok ? *(const float4*)(xp0 + kb) : make_float4(0.f, 0.f, 0.f, 0.f);
        ra1 = ok ? *(const float4*)(xp1 + kb) : make_float4(0.f, 0.f, 0.f, 0.f);
        rb0 = *(const int4*)(bp0 + kb);      // W1t zero-padded to KP
        rb1 = *(const int4*)(bp1 + kb);
    }

    int buf = 0;
    for (int s = s0; s < s1; ++s) {
        *(short4*)(&As[buf][tid * 4])        = cvt4(ra0);
        *(short4*)(&As[buf][tid * 4 + 2048]) = cvt4(ra1);
        *(int4*)(&Bs[buf][tid * 8])          = rb0;
        *(int4*)(&Bs[buf][tid * 8 + 4096])   = rb1;
        if (s + 1 < s1) {
            int kb = (s + 1) * 32;
            bool ok = (kb + k4 + 4 <= KREAL);
            ra0 = ok ? *(const float4*)(xp0 + kb) : make_float4(0.f, 0.f, 0.f, 0.f);
            ra1 = ok ? *(const float4*)(xp1 + kb) : make_float4(0.f, 0.f, 0.f, 0.f);
            rb0 = *(const int4*)(bp0 + kb);
            rb1 = *(const int4*)(bp1 + kb);
        }
        __syncthreads();
        frag_ab af[4], bfr[4];
#pragma unroll
        for (int mt = 0; mt < 4; mt++)
            af[mt] = *(const frag_ab*)(&As[buf][(wr * 64 + mt * 16 + lrow) * 32 + lq * 8]);
#pragma unroll
        for (int nt = 0; nt < 4; nt++)
            bfr[nt] = *(const frag_ab*)(&Bs[buf][(wc * 64 + nt * 16 + lrow) * 32 + lq * 8]);
#pragma unroll
        for (int mt = 0; mt < 4; mt++)
#pragma unroll
            for (int nt = 0; nt < 4; nt++)
                acc[mt][nt] = __builtin_amdgcn_mfma_f32_16x16x32_bf16(
                    af[mt], bfr[nt], acc[mt][nt], 0, 0, 0);
        buf ^= 1;
    }

    // epilogue: D row = quad*4 + reg, col = lane&15 (m89-verified layout)
#pragma unroll
    for (int mt = 0; mt < 4; mt++)
#pragma unroll
        for (int nt = 0; nt < 4; nt++)
#pragma unroll
            for (int r = 0; r < 4; r++) {
                int row = m0 + wr * 64 + mt * 16 + lq * 4 + r;
                int col = wc * 64 + nt * 16 + lrow;
                pout[((long)ch * BATCH + row) * SDIM + col] = acc[mt][nt][r];
            }
}

// ---------------------------------------------------------------------------
// Kernel 2: batched pathway expert + drug head. One block = 32 same-pathway
// samples (via bucket), 256 threads. Wp[p] is read ONCE per 32 samples
// (L2 traffic 1.07 GB -> 34 MB); h rows staged in LDS (stride 260 = no
// bank conflict on write; broadcast on read).
// ---------------------------------------------------------------------------
__global__ __launch_bounds__(256)
void stage2(const float* __restrict__ pout, const float* __restrict__ b1,
            const float* __restrict__ Wp, const float* __restrict__ bp,
            const float* __restrict__ Wd, const float* __restrict__ bd,
            const int* __restrict__ drug_idx,
            const int* __restrict__ ord, const int* __restrict__ blk_p,
            float* __restrict__ out, int nch) {
    int g = blockIdx.x;
    int p = blk_p[g];
    if (p < 0) return;

    __shared__ float hs[S2S][260];       // padded: +4 breaks 8-way write conflict
    __shared__ float pw[S2S][132];
    __shared__ int   sidx[S2S];

    int t = threadIdx.x;
    if (t < S2S) sidx[t] = ord[g * S2S + t];
    __syncthreads();

    int si = t >> 3, l8 = t & 7;
    int b = sidx[si];

    // ---- h phase: 8 threads per sample, float4 strips
#pragma unroll
    for (int v = 0; v < 8; v++) {
        int i = (l8 + v * 8) * 4;        // 0..255 step float4
        float4 a = *(const float4*)(b1 + i);
        if (b >= 0) {
            for (int c = 0; c < nch; c++) {
                float4 q = *(const float4*)(pout + ((long)c * BATCH + b) * SDIM + i);
                a.x += q.x; a.y += q.y; a.z += q.z; a.w += q.w;
            }
        }
        float4 r;
        r.x = fmaxf(a.x, 0.f); r.y = fmaxf(a.y, 0.f);
        r.z = fmaxf(a.z, 0.f); r.w = fmaxf(a.w, 0.f);
        *(float4*)(&hs[si][i]) = r;
    }
    __syncthreads();

    // ---- pathway matmul: thread = output col d for 16 samples
    int d = t & 127, half = t >> 7;
    const float* wpc = Wp + (long)p * SDIM * PDIM + d;
    float acc[16];
#pragma unroll
    for (int jj = 0; jj < 16; jj++) acc[jj] = 0.f;
    for (int s4 = 0; s4 < SDIM; s4 += 4) {
        float w0 = wpc[(s4 + 0) * PDIM];
        float w1 = wpc[(s4 + 1) * PDIM];
        float w2 = wpc[(s4 + 2) * PDIM];
        float w3 = wpc[(s4 + 3) * PDIM];
#pragma unroll
        for (int jj = 0; jj < 16; jj++) {
            float4 h4 = *(const float4*)(&hs[half * 16 + jj][s4]);   // broadcast
            acc[jj] = fmaf(h4.x, w0, acc[jj]);
            acc[jj] = fmaf(h4.y, w1, acc[jj]);
            acc[jj] = fmaf(h4.z, w2, acc[jj]);
            acc[jj] = fmaf(h4.w, w3, acc[jj]);
        }
    }
    float bpv = bp[p * PDIM + d];
#pragma unroll
    for (int jj = 0; jj < 16; jj++)
        pw[half * 16 + jj][d] = fmaxf(acc[jj] + bpv, 0.f);
    __syncthreads();

    // ---- drug head: 8 threads per sample, shuffle-reduce width 8
    if (b >= 0) {
        int drug = drug_idx[b];
        const float* wd = Wd + drug * PDIM;
        float v = 0.f;
#pragma unroll
        for (int k = 0; k < 16; k++) {
            int dd = l8 + k * 8;
            v = fmaf(pw[si][dd], wd[dd], v);
        }
        v += __shfl_down(v, 4, 8);
        v += __shfl_down(v, 2, 8);
        v += __shfl_down(v, 1, 8);
        if (l8 == 0) out[b] = v + bd[drug];
    }
}

// ---------------------------------------------------------------------------
extern "C" void kernel_launch(void* const* d_in, const int* in_sizes, int n_in,
                              void* d_out, int out_size, void* d_ws, size_t ws_size,
                              hipStream_t stream) {
    const float* x    = (const float*)d_in[0];
    const int*   drug = (const int*)d_in[1];
    const float* W1   = (const float*)d_in[2];
    const float* b1   = (const float*)d_in[3];
    const float* Wp   = (const float*)d_in[4];
    const float* bp   = (const float*)d_in[5];
    const float* Wd   = (const float*)d_in[6];
    const float* bd   = (const float*)d_in[7];
    const int*   d2p  = (const int*)d_in[8];
    float* out = (float*)d_out;

    size_t pchunk    = (size_t)BATCH * SDIM * sizeof(float);    // 8 MB per K-chunk
    size_t w1t_bytes = (size_t)SDIM * KP * sizeof(short);       // ~9.3 MB
    size_t ordb      = (size_t)MAXBLK * S2S * sizeof(int);
    size_t blkb      = (size_t)MAXBLK * sizeof(int);
    int nch = 4;
    if (ws_size < w1t_bytes + 4 * pchunk + ordb + blkb + 256) {
        long avail = (long)ws_size - (long)(w1t_bytes + ordb + blkb + 256);
        nch = (int)(avail / (long)pchunk);
        if (nch < 1) nch = 1;
        if (nch > 4) nch = 4;
    }
    float* pout  = (float*)d_ws;
    short* W1t   = (short*)((char*)d_ws + (size_t)nch * pchunk);
    int*   ord   = (int*)((char*)d_ws + (size_t)nch * pchunk + w1t_bytes);
    int*   blk_p = ord + MAXBLK * S2S;

    hipLaunchKernelGGL(transpose_w1, dim3(NSTEPS, SDIM / 32), dim3(256), 0, stream,
                       W1, W1t);
    hipLaunchKernelGGL(bucket, dim3(1), dim3(1024), 0, stream,
                       drug, d2p, ord, blk_p);
    hipLaunchKernelGGL(gemm1, dim3(MBLK * nch), dim3(512), 0, stream,
                       x, W1t, pout, nch);
    hipLaunchKernelGGL(stage2, dim3(MAXBLK), dim3(256), 0, stream,
                       pout, b1, Wp, bp, Wd, bd, drug, ord, blk_p, out, nch);
}

// Round 3
// 896.694 us; speedup vs baseline: 1.0238x; 1.0238x over previous
//
#include <hip/hip_runtime.h>

#define KREAL 19000
#define KP    19008      // K padded to multiple of 32
#define NSTEPS 594       // KP / 32
#define BM 128
#define BN 256
#define MBLK 64          // 8192 / BM
#define BATCH 8192
#define SDIM 256
#define PDIM 128
#define NPW  16
#define S2S  32          // samples per stage2 block
#define MAXBLK 272       // exact bound: 8192/32 + 16 (per-pathway pad)

typedef __attribute__((ext_vector_type(8))) short frag_ab;   // 8 bf16 = 4 VGPRs
typedef __attribute__((ext_vector_type(4))) float frag_cd;   // 4 fp32 acc

static __device__ __forceinline__ short f2bf(float f) {
    union { float f; unsigned u; } cv; cv.f = f;
    unsigned u = cv.u;
    u += 0x7fffu + ((u >> 16) & 1u);   // round-to-nearest-even
    return (short)(u >> 16);
}

static __device__ __forceinline__ short4 cvt4(float4 v) {
    short4 p;
    p.x = f2bf(v.x); p.y = f2bf(v.y); p.z = f2bf(v.z); p.w = f2bf(v.w);
    return p;
}

// ---------------------------------------------------------------------------
// Kernel 0: W1 [19000][256] fp32 -> W1t [256][19008] bf16 (zero-padded K).
// Block (0,0) additionally initializes ord/blk_p/gpos for the bucketing that
// runs inside gemm1 (this kernel strictly precedes gemm1 in the stream).
// ---------------------------------------------------------------------------
__global__ void transpose_w1(const float* __restrict__ W1, short* __restrict__ W1t,
                             int* __restrict__ ord, int* __restrict__ blk_p,
                             int* __restrict__ gpos) {
    __shared__ float tile[32][33];
    int k0 = blockIdx.x * 32;
    int n0 = blockIdx.y * 32;
    int tx = threadIdx.x & 31;
    int ty = threadIdx.x >> 5;           // 0..7

    if (blockIdx.x == 0 && blockIdx.y == 0) {
        for (int i = threadIdx.x; i < MAXBLK * S2S; i += 256) ord[i] = -1;
        for (int i = threadIdx.x; i < MAXBLK; i += 256) blk_p[i] = -1;
        if (threadIdx.x < NPW) gpos[threadIdx.x] = 0;
    }

#pragma unroll
    for (int i = 0; i < 32; i += 8) {
        int k = k0 + ty + i;
        tile[ty + i][tx] = (k < KREAL) ? W1[(long)k * SDIM + n0 + tx] : 0.f;
    }
    __syncthreads();
#pragma unroll
    for (int i = 0; i < 32; i += 8) {
        int n = n0 + ty + i;
        W1t[(long)n * KP + k0 + tx] = f2bf(tile[tx][ty + i]);
    }
}

// ---------------------------------------------------------------------------
// Kernel 1: split-K GEMM partials + (hidden) pathway bucketing.
// Blocks [0, MBLK*nch): pout[ch][8192][256] = x @ W1 chunk. Pipelined
//   double-buffered LDS, one barrier per K-step, reg-staged early loads.
// Blocks [MBLK*nch, +16): one per pathway p — ballot-based counting sort of
//   samples into ord[] (grouped by pathway, segments padded to 32), blk_p[g]=
//   pathway of stage2 block g. Runs in ~2 us under the BW-bound GEMM.
// ---------------------------------------------------------------------------
__global__ __launch_bounds__(512, 2)
void gemm1(const float* __restrict__ x, const short* __restrict__ W1t,
           float* __restrict__ pout,
           const int* __restrict__ drug_idx, const int* __restrict__ d2p,
           int* __restrict__ ord, int* __restrict__ blk_p, int* __restrict__ gpos,
           int nch) {
    __shared__ short As[2][BM * 32];     // 2 x 8 KB   [m][k]
    __shared__ short Bs[2][BN * 32];     // 2 x 16 KB  [n][k] (B^T layout)

    int bid  = blockIdx.x;
    int nblk = MBLK * nch;
    int tid  = threadIdx.x;

    if (bid >= nblk) {
        // ---------------- bucket block for pathway p ----------------
        int p = bid - nblk;
        __shared__ int hist[8][NPW];
        __shared__ int cnt[NPW];
        int w = tid >> 6, lane = tid & 63;
        if (tid < 8 * NPW) ((int*)hist)[tid] = 0;
        __syncthreads();

        int q[16];
#pragma unroll
        for (int r = 0; r < 16; r++)
            q[r] = d2p[drug_idx[tid + 512 * r]];

#pragma unroll 1
        for (int r = 0; r < 16; r++) {
#pragma unroll
            for (int pw = 0; pw < NPW; pw++) {
                unsigned long long m = __ballot(q[r] == pw);
                if (lane == 0) hist[w][pw] += __popcll(m);
            }
        }
        __syncthreads();
        if (tid < NPW) {
            int c = 0;
            for (int w2 = 0; w2 < 8; w2++) c += hist[w2][tid];
            cnt[tid] = c;
        }
        __syncthreads();

        int pstart = 0;
        for (int qq = 0; qq < p; qq++) pstart += (cnt[qq] + 31) >> 5;
        int nb = (cnt[p] + 31) >> 5;
        if (tid < nb) blk_p[pstart + tid] = p;

        int base0 = pstart * S2S;
#pragma unroll 1
        for (int r = 0; r < 16; r++) {
            unsigned long long m = __ballot(q[r] == p);
            int rank = __popcll(m & ((1ull << lane) - 1ull));
            int wcnt = __popcll(m);
            int wbase = 0;
            if (lane == 0 && wcnt) wbase = atomicAdd(gpos + p, wcnt);
            wbase = __shfl(wbase, 0, 64);
            if (q[r] == p) ord[base0 + wbase + rank] = tid + 512 * r;
        }
        return;
    }

    // ---------------- GEMM block ----------------
    int mb, ch;
    if (nch == 4) {
        // XCD-aware decode: chunk ch pinned to one XCD pair -> its 2.3 MB
        // W1t slice stays L2-resident. Bijective: bid = slot*8 + xcd.
        int xcd  = bid & 7;
        int slot = bid >> 3;             // 0..31
        ch = xcd >> 1;                   // 0..3
        mb = ((xcd & 1) << 5) | slot;    // 0..63
    } else {
        mb = bid % MBLK;
        ch = bid / MBLK;
    }
    int m0 = mb * BM;
    int s0 = (NSTEPS * ch) / nch;
    int s1 = (NSTEPS * (ch + 1)) / nch;

    int wave = tid >> 6;
    int lane = tid & 63;
    int wr = wave >> 2, wc = wave & 3;
    int lrow = lane & 15;
    int lq   = lane >> 4;                // quad 0..3

    int k4 = (tid & 7) << 2;                                   // 0..28 floats
    const float* xp0 = x + (long)(m0 + (tid >> 3)) * KREAL + k4;
    const float* xp1 = xp0 + (long)64 * KREAL;
    const short* bp0 = W1t + (long)(tid >> 2) * KP + ((tid & 3) << 3);
    const short* bp1 = bp0 + (long)128 * KP;

    frag_cd acc[4][4];
#pragma unroll
    for (int i = 0; i < 4; i++)
#pragma unroll
        for (int j = 0; j < 4; j++) acc[i][j] = (frag_cd)(0.f);

    float4 ra0, ra1;
    int4   rb0, rb1;
    {   // prologue: load step s0 into regs
        int kb = s0 * 32;
        bool ok = (kb + k4 + 4 <= KREAL);
        ra0 = ok ? *(const float4*)(xp0 + kb) : make_float4(0.f, 0.f, 0.f, 0.f);
        ra1 = ok ? *(const float4*)(xp1 + kb) : make_float4(0.f, 0.f, 0.f, 0.f);
        rb0 = *(const int4*)(bp0 + kb);      // W1t zero-padded to KP
        rb1 = *(const int4*)(bp1 + kb);
    }

    int buf = 0;
    for (int s = s0; s < s1; ++s) {
        *(short4*)(&As[buf][tid * 4])        = cvt4(ra0);
        *(short4*)(&As[buf][tid * 4 + 2048]) = cvt4(ra1);
        *(int4*)(&Bs[buf][tid * 8])          = rb0;
        *(int4*)(&Bs[buf][tid * 8 + 4096])   = rb1;
        if (s + 1 < s1) {
            int kb = (s + 1) * 32;
            bool ok = (kb + k4 + 4 <= KREAL);
            ra0 = ok ? *(const float4*)(xp0 + kb) : make_float4(0.f, 0.f, 0.f, 0.f);
            ra1 = ok ? *(const float4*)(xp1 + kb) : make_float4(0.f, 0.f, 0.f, 0.f);
            rb0 = *(const int4*)(bp0 + kb);
            rb1 = *(const int4*)(bp1 + kb);
        }
        __syncthreads();
        frag_ab af[4], bfr[4];
#pragma unroll
        for (int mt = 0; mt < 4; mt++)
            af[mt] = *(const frag_ab*)(&As[buf][(wr * 64 + mt * 16 + lrow) * 32 + lq * 8]);
#pragma unroll
        for (int nt = 0; nt < 4; nt++)
            bfr[nt] = *(const frag_ab*)(&Bs[buf][(wc * 64 + nt * 16 + lrow) * 32 + lq * 8]);
#pragma unroll
        for (int mt = 0; mt < 4; mt++)
#pragma unroll
            for (int nt = 0; nt < 4; nt++)
                acc[mt][nt] = __builtin_amdgcn_mfma_f32_16x16x32_bf16(
                    af[mt], bfr[nt], acc[mt][nt], 0, 0, 0);
        buf ^= 1;
    }

    // epilogue: D row = quad*4 + reg, col = lane&15 (m89-verified layout)
#pragma unroll
    for (int mt = 0; mt < 4; mt++)
#pragma unroll
        for (int nt = 0; nt < 4; nt++)
#pragma unroll
            for (int r = 0; r < 4; r++) {
                int row = m0 + wr * 64 + mt * 16 + lq * 4 + r;
                int col = wc * 64 + nt * 16 + lrow;
                pout[((long)ch * BATCH + row) * SDIM + col] = acc[mt][nt][r];
            }
}

// ---------------------------------------------------------------------------
// Kernel 2: batched pathway expert + drug head. One block = 32 same-pathway
// samples, 256 threads. Wp[p] read once per 32 samples; all 4 waves stream
// identical Wp addresses (L1 serves 3 of 4). Thread = 2 cols x 8 samples:
// FMA-bound (512 ds_read_b128/thread, 4096 FMA/thread). Per-(sample,col)
// s-summation order identical to previous versions -> bitwise-stable.
// ---------------------------------------------------------------------------
__global__ __launch_bounds__(256)
void stage2(const float* __restrict__ pout, const float* __restrict__ b1,
            const float* __restrict__ Wp, const float* __restrict__ bp,
            const float* __restrict__ Wd, const float* __restrict__ bd,
            const int* __restrict__ drug_idx,
            const int* __restrict__ ord, const int* __restrict__ blk_p,
            float* __restrict__ out, int nch) {
    int g = blockIdx.x;
    int p = blk_p[g];
    if (p < 0) return;

    __shared__ float hs[S2S][260];       // stride 260: no write conflicts
    __shared__ float pw[S2S][132];
    __shared__ int   sidx[S2S];

    int t = threadIdx.x;
    if (t < S2S) sidx[t] = ord[g * S2S + t];
    __syncthreads();

    int si = t >> 3, l8 = t & 7;
    int b = sidx[si];

    // ---- h phase: 8 threads per sample, float4 strips
#pragma unroll
    for (int v = 0; v < 8; v++) {
        int i = (l8 + v * 8) * 4;        // 0..255 step float4
        float4 a = *(const float4*)(b1 + i);
        if (b >= 0) {
            for (int c = 0; c < nch; c++) {
                float4 q = *(const float4*)(pout + ((long)c * BATCH + b) * SDIM + i);
                a.x += q.x; a.y += q.y; a.z += q.z; a.w += q.w;
            }
        }
        float4 r;
        r.x = fmaxf(a.x, 0.f); r.y = fmaxf(a.y, 0.f);
        r.z = fmaxf(a.z, 0.f); r.w = fmaxf(a.w, 0.f);
        *(float4*)(&hs[si][i]) = r;
    }
    __syncthreads();

    // ---- pathway matmul: thread = cols {d, d+64} for 8 samples
    int d   = t & 63;
    int grp = t >> 6;                    // samples grp*8 .. grp*8+7
    const float* wpc = Wp + (long)p * SDIM * PDIM + d;
    float acc0[8], acc1[8];
#pragma unroll
    for (int jj = 0; jj < 8; jj++) { acc0[jj] = 0.f; acc1[jj] = 0.f; }
#pragma unroll 2
    for (int s4 = 0; s4 < SDIM; s4 += 4) {
        float w00 = wpc[(s4 + 0) * PDIM], w01 = wpc[(s4 + 0) * PDIM + 64];
        float w10 = wpc[(s4 + 1) * PDIM], w11 = wpc[(s4 + 1) * PDIM + 64];
        float w20 = wpc[(s4 + 2) * PDIM], w21 = wpc[(s4 + 2) * PDIM + 64];
        float w30 = wpc[(s4 + 3) * PDIM], w31 = wpc[(s4 + 3) * PDIM + 64];
#pragma unroll
        for (int jj = 0; jj < 8; jj++) {
            float4 h4 = *(const float4*)(&hs[grp * 8 + jj][s4]);   // broadcast
            acc0[jj] = fmaf(h4.x, w00, acc0[jj]);
            acc1[jj] = fmaf(h4.x, w01, acc1[jj]);
            acc0[jj] = fmaf(h4.y, w10, acc0[jj]);
            acc1[jj] = fmaf(h4.y, w11, acc1[jj]);
            acc0[jj] = fmaf(h4.z, w20, acc0[jj]);
            acc1[jj] = fmaf(h4.z, w21, acc1[jj]);
            acc0[jj] = fmaf(h4.w, w30, acc0[jj]);
            acc1[jj] = fmaf(h4.w, w31, acc1[jj]);
        }
    }
    float bpv0 = bp[p * PDIM + d], bpv1 = bp[p * PDIM + d + 64];
#pragma unroll
    for (int jj = 0; jj < 8; jj++) {
        pw[grp * 8 + jj][d]      = fmaxf(acc0[jj] + bpv0, 0.f);
        pw[grp * 8 + jj][d + 64] = fmaxf(acc1[jj] + bpv1, 0.f);
    }
    __syncthreads();

    // ---- drug head: 8 threads per sample, shuffle-reduce width 8
    if (b >= 0) {
        int drug = drug_idx[b];
        const float* wd = Wd + drug * PDIM;
        float v = 0.f;
#pragma unroll
        for (int k = 0; k < 16; k++) {
            int dd = l8 + k * 8;
            v = fmaf(pw[si][dd], wd[dd], v);
        }
        v += __shfl_down(v, 4, 8);
        v += __shfl_down(v, 2, 8);
        v += __shfl_down(v, 1, 8);
        if (l8 == 0) out[b] = v + bd[drug];
    }
}

// ---------------------------------------------------------------------------
extern "C" void kernel_launch(void* const* d_in, const int* in_sizes, int n_in,
                              void* d_out, int out_size, void* d_ws, size_t ws_size,
                              hipStream_t stream) {
    const float* x    = (const float*)d_in[0];
    const int*   drug = (const int*)d_in[1];
    const float* W1   = (const float*)d_in[2];
    const float* b1   = (const float*)d_in[3];
    const float* Wp   = (const float*)d_in[4];
    const float* bp   = (const float*)d_in[5];
    const float* Wd   = (const float*)d_in[6];
    const float* bd   = (const float*)d_in[7];
    const int*   d2p  = (const int*)d_in[8];
    float* out = (float*)d_out;

    size_t pchunk    = (size_t)BATCH * SDIM * sizeof(float);    // 8 MB per K-chunk
    size_t w1t_bytes = (size_t)SDIM * KP * sizeof(short);       // ~9.3 MB
    size_t ordb      = (size_t)MAXBLK * S2S * sizeof(int);
    size_t blkb      = (size_t)MAXBLK * sizeof(int);
    size_t gposb     = (size_t)NPW * sizeof(int);
    int nch = 4;
    if (ws_size < w1t_bytes + 4 * pchunk + ordb + blkb + gposb + 256) {
        long avail = (long)ws_size - (long)(w1t_bytes + ordb + blkb + gposb + 256);
        nch = (int)(avail / (long)pchunk);
        if (nch < 1) nch = 1;
        if (nch > 4) nch = 4;
    }
    float* pout  = (float*)d_ws;
    short* W1t   = (short*)((char*)d_ws + (size_t)nch * pchunk);
    int*   ord   = (int*)((char*)d_ws + (size_t)nch * pchunk + w1t_bytes);
    int*   blk_p = ord + MAXBLK * S2S;
    int*   gpos  = blk_p + MAXBLK;

    hipLaunchKernelGGL(transpose_w1, dim3(NSTEPS, SDIM / 32), dim3(256), 0, stream,
                       W1, W1t, ord, blk_p, gpos);
    hipLaunchKernelGGL(gemm1, dim3(MBLK * nch + NPW), dim3(512), 0, stream,
                       x, W1t, pout, drug, d2p, ord, blk_p, gpos, nch);
    hipLaunchKernelGGL(stage2, dim3(MAXBLK), dim3(256), 0, stream,
                       pout, b1, Wp, bp, Wd, bd, drug, ord, blk_p, out, nch);
}